// Round 9
// baseline (25.189 us; speedup 1.0000x reference)
//
#include <hip/hip_runtime.h>

typedef short bf16x8 __attribute__((ext_vector_type(8)));
typedef float f32x4 __attribute__((ext_vector_type(4)));
typedef ushort u16x8 __attribute__((ext_vector_type(8)));

#define MFMA16(A, B, C) __builtin_amdgcn_mfma_f32_16x16x32_bf16((A), (B), (C), 0, 0, 0)

static __device__ __forceinline__ ushort f2bf(float f) {
    unsigned u = __builtin_bit_cast(unsigned, f);
    unsigned r = (u + 0x7FFFu + ((u >> 16) & 1u)) >> 16;
    return (ushort)r;
}
static __device__ __forceinline__ unsigned pk2(float a, float b) {
    return (unsigned)f2bf(a) | ((unsigned)f2bf(b) << 16);
}
static __device__ __forceinline__ bf16x8 ldg8(const ushort* p) {
    uint4 u = *(const uint4*)p;
    return __builtin_bit_cast(bf16x8, u);
}

// ---- workspace layout (bytes) ----
// kT : [2][24][32pad][512] bf16            @ 0        size 1572864
// v4 : [4][2][512][25][32pad] bf16         @ 1572864  size 6553600
#define OFF_KT 0
#define OFF_V4 1572864
#define WS_NEED 8126464

// Fused K/V prep (R4-identical, proven):
//   blocks [0, 576)     : k -> kT bf16 [2][24][32pad][512] (pad cols unwritten:
//                         they only feed softmax-masked tap positions)
//   blocks [576, 2176)  : v -> v4 gather [4][2][512][25][32pad], full coverage
__global__ __launch_bounds__(256) void prep(const float* __restrict__ k,
                                            const float* __restrict__ v,
                                            ushort* __restrict__ kt,
                                            ushort* __restrict__ v4) {
    __shared__ float tile[32][33];
    int bid = blockIdx.x;

    if (bid < 576) {
        int b = bid / 288;
        int rem = bid % 288;
        int p0 = (rem / 16) * 32;
        int c0 = (rem % 16) * 32;
        int tx = threadIdx.x & 31, tw = threadIdx.x >> 5;
#pragma unroll
        for (int i = 0; i < 4; ++i) {
            int r = tw + i * 8;
            tile[r][tx] = k[(size_t)(b * 512 + c0 + r) * 576 + p0 + tx];
        }
        __syncthreads();
#pragma unroll
        for (int i = 0; i < 4; ++i) {
            int r = tw + i * 8;
            int pix = p0 + r;
            int kr = pix / 24, kc = pix % 24;
            kt[((size_t)(b * 24 + kr) * 32 + kc) * 512 + c0 + tx] = f2bf(tile[tx][r]);
        }
    } else {
        int tid = (bid - 576) * 256 + threadIdx.x;  // 409600 threads total
        int col0 = (tid & 3) * 8;
        int rowlin = tid >> 2;
        int kr = rowlin % 25;
        int c = (rowlin / 25) % 512;
        int b = (rowlin / (25 * 512)) & 1;
        int s = rowlin / (25 * 512 * 2);
        const float* src = v + (size_t)(b * 512 + c) * 576 + kr * 24;
        u16x8 w;
#pragma unroll
        for (int j = 0; j < 8; ++j) {
            int srcc = col0 + j + 2 * s;
            w[j] = (kr < 24 && srcc < 24) ? f2bf(src[srcc]) : (ushort)0;
        }
        *(u16x8*)&v4[(size_t)rowlin * 32 + col0] = w;
    }
}

// One wave per (4x8 pixel tile, head): 1152 blocks x 64 threads.
// The 10-row K window and all 20 V fragments are SHARED across the tile's
// two 2x8 pixel-groups (A = rows 0,1; B = rows 2,3) -> kt/v4 load count per
// output halves vs the 2x8-tile version; two independent chains per wave
// double ILP to compensate for the halved wave count.
__global__ __launch_bounds__(64) void attn(const float* __restrict__ q,
                                           const ushort* __restrict__ kt,
                                           const ushort* __restrict__ v4,
                                           float* __restrict__ out) {
    __shared__ __align__(16) unsigned Plds[16][84];  // one pixel-group's P at a time

    int j = blockIdx.x;  // [0,1152)
    int h = j & 7;
    int t = j >> 3;      // [0,144)
    int tx = t % 6;
    int tyb = t / 6;     // [0,24)
    int ty4 = tyb % 12;
    int b = tyb / 12;

    int l = threadIdx.x;
    int pix = l & 15, g = l >> 4;
    int px = pix & 7, py = pix >> 3;
    int x = tx * 8 + px;

    int rp0 = ty4 * 2;                          // row-pair index of group A
    int sr = min(max(rp0 - 4, 0), 15);          // K-window base row (groups share)
    int d1 = min(max(rp0 - 3, 0), 15) - sr;     // group-B row offset: 0 or 1

    int sw0 = min(max(4 * tx - 4, 0), 15);
    int swe = sw0 & ~1;
    int sw = min(max((x >> 1) - 4, 0), 15);
    int dx = sw - swe;                          // valid tap cols = [dx, dx+8]
    int s2 = swe & 6, scopy = s2 >> 1, colbase = swe - s2;

    // ---- Q gather for both row-groups (straight from q[b][c][y][x]) ----
    int yA = ty4 * 4 + py, yB = yA + 2;
    const float* qsA = q + (size_t)(b * 512 + h * 64 + g * 8) * 2304 + yA * 48 + x;
    float a0[8], a1[8], b0[8], b1[8];
#pragma unroll
    for (int i = 0; i < 8; ++i) a0[i] = qsA[(size_t)i * 2304];
#pragma unroll
    for (int i = 0; i < 8; ++i) a1[i] = qsA[(size_t)(i + 32) * 2304];
#pragma unroll
    for (int i = 0; i < 8; ++i) b0[i] = qsA[(size_t)i * 2304 + 96];
#pragma unroll
    for (int i = 0; i < 8; ++i) b1[i] = qsA[(size_t)(i + 32) * 2304 + 96];
    bf16x8 q0A, q1A, q0B, q1B;
#pragma unroll
    for (int i = 0; i < 8; ++i) {
        q0A[i] = (short)f2bf(a0[i]);
        q1A[i] = (short)f2bf(a1[i]);
        q0B[i] = (short)f2bf(b0[i]);
        q1B[i] = (short)f2bf(b1[i]);
    }

    // ---- QK^T (swapped): S^T[tap][pixel]; 10 mtiles share one kt load ----
    f32x4 scA[9], scB[10];
#pragma unroll
    for (int m = 0; m < 10; ++m) {
        int krow = b * 24 + min(sr + m, 23);  // clamp: row only feeds masked taps
        int koff = ((krow << 5) + swe + pix) * 512 + h * 64 + g * 8;
        bf16x8 k0 = ldg8(kt + koff), k1 = ldg8(kt + koff + 32);
        if (m < 9) {
            f32x4 a = {0.f, 0.f, 0.f, 0.f};
            a = MFMA16(k0, q0A, a);
            a = MFMA16(k1, q1A, a);
            scA[m] = a;
        }
        f32x4 a2 = {0.f, 0.f, 0.f, 0.f};
        a2 = MFMA16(k0, q0B, a2);
        a2 = MFMA16(k1, q1B, a2);
        scB[m] = a2;
    }

    const float C2 = 0.18033688011112042f;  // 0.125 * log2(e)

    // ---- softmax A (rows sr..sr+8 all valid; col mask only) ----
    float mxA = -3.0e38f;
#pragma unroll
    for (int r = 0; r < 4; ++r) {
        if ((unsigned)(g * 4 + r - dx) <= 8u) {
#pragma unroll
            for (int m = 0; m < 9; ++m) mxA = fmaxf(mxA, scA[m][r]);
        }
    }
    mxA = fmaxf(mxA, __shfl_xor(mxA, 16));
    mxA = fmaxf(mxA, __shfl_xor(mxA, 32));
    float sumA = 0.f;
#pragma unroll
    for (int m = 0; m < 9; ++m) {
#pragma unroll
        for (int r = 0; r < 4; ++r) {
            bool valid = (unsigned)(g * 4 + r - dx) <= 8u;
            float p = valid ? exp2f((scA[m][r] - mxA) * C2) : 0.f;
            scA[m][r] = p;
            sumA += p;
        }
    }
    sumA += __shfl_xor(sumA, 16);
    sumA += __shfl_xor(sumA, 32);
    float invdA = 1.0f / sumA;

    // ---- preload ALL 20 V fragments (reused by both PV passes) ----
    bf16x8 vf[5][4];
#pragma unroll
    for (int ks = 0; ks < 5; ++ks) {
        int tap0 = ks * 32 + g * 8;
        int tr = tap0 >> 4, tc0 = tap0 & 15;
#pragma unroll
        for (int md = 0; md < 4; ++md) {
            int ch = h * 64 + md * 16 + pix;
            vf[ks][md] = ldg8(v4 + ((size_t)((scopy * 2 + b) * 512 + ch) * 25 + sr + tr) * 32 + colbase + tc0);
        }
    }

    // ---- P_A -> LDS (mtile 9 = zeros for group A) ----
#pragma unroll
    for (int m = 0; m < 9; ++m) {
        uint2 w;
        w.x = pk2(scA[m][0], scA[m][1]);
        w.y = pk2(scA[m][2], scA[m][3]);
        *(uint2*)&Plds[pix][m * 8 + g * 2] = w;
    }
    *(uint2*)&Plds[pix][72 + g * 2] = make_uint2(0u, 0u);

    // ---- PV_A ----
    f32x4 o[4] = {{0.f, 0.f, 0.f, 0.f}, {0.f, 0.f, 0.f, 0.f}, {0.f, 0.f, 0.f, 0.f}, {0.f, 0.f, 0.f, 0.f}};
#pragma unroll
    for (int ks = 0; ks < 5; ++ks) {
        uint4 pw = *(const uint4*)&Plds[pix][ks * 16 + g * 4];
        bf16x8 pf = __builtin_bit_cast(bf16x8, pw);
#pragma unroll
        for (int md = 0; md < 4; ++md) o[md] = MFMA16(vf[ks][md], pf, o[md]);
    }
#pragma unroll
    for (int md = 0; md < 4; ++md) {
#pragma unroll
        for (int r = 0; r < 4; ++r) {
            int d = md * 16 + g * 4 + r;
            out[((size_t)(b * 512 + h * 64 + d) * 48 + yA) * 48 + x] = o[md][r] * invdA;
        }
    }

    // ---- softmax B (rows sr+d1..sr+d1+8 valid; row + col mask) ----
    float mxB = -3.0e38f;
#pragma unroll
    for (int m = 0; m < 10; ++m) {
#pragma unroll
        for (int r = 0; r < 4; ++r) {
            if (((unsigned)(g * 4 + r - dx) <= 8u) && ((unsigned)(m - d1) <= 8u))
                mxB = fmaxf(mxB, scB[m][r]);
        }
    }
    mxB = fmaxf(mxB, __shfl_xor(mxB, 16));
    mxB = fmaxf(mxB, __shfl_xor(mxB, 32));
    float sumB = 0.f;
#pragma unroll
    for (int m = 0; m < 10; ++m) {
#pragma unroll
        for (int r = 0; r < 4; ++r) {
            bool valid = ((unsigned)(g * 4 + r - dx) <= 8u) && ((unsigned)(m - d1) <= 8u);
            float p = valid ? exp2f((scB[m][r] - mxB) * C2) : 0.f;
            scB[m][r] = p;
            sumB += p;
        }
    }
    sumB += __shfl_xor(sumB, 16);
    sumB += __shfl_xor(sumB, 32);
    float invdB = 1.0f / sumB;

    // ---- P_B -> LDS (overwrites P_A; same-wave ordering via lgkmcnt) ----
#pragma unroll
    for (int m = 0; m < 10; ++m) {
        uint2 w;
        w.x = pk2(scB[m][0], scB[m][1]);
        w.y = pk2(scB[m][2], scB[m][3]);
        *(uint2*)&Plds[pix][m * 8 + g * 2] = w;
    }

    // ---- PV_B (same vf registers, no reload) ----
    f32x4 o2[4] = {{0.f, 0.f, 0.f, 0.f}, {0.f, 0.f, 0.f, 0.f}, {0.f, 0.f, 0.f, 0.f}, {0.f, 0.f, 0.f, 0.f}};
#pragma unroll
    for (int ks = 0; ks < 5; ++ks) {
        uint4 pw = *(const uint4*)&Plds[pix][ks * 16 + g * 4];
        bf16x8 pf = __builtin_bit_cast(bf16x8, pw);
#pragma unroll
        for (int md = 0; md < 4; ++md) o2[md] = MFMA16(vf[ks][md], pf, o2[md]);
    }
#pragma unroll
    for (int md = 0; md < 4; ++md) {
#pragma unroll
        for (int r = 0; r < 4; ++r) {
            int d = md * 16 + g * 4 + r;
            out[((size_t)(b * 512 + h * 64 + d) * 48 + yB) * 48 + x] = o2[md][r] * invdB;
        }
    }
}

extern "C" void kernel_launch(void* const* d_in, const int* in_sizes, int n_in,
                              void* d_out, int out_size, void* d_ws, size_t ws_size,
                              hipStream_t stream) {
    const float* q = (const float*)d_in[0];
    const float* k = (const float*)d_in[1];
    const float* v = (const float*)d_in[2];
    float* out = (float*)d_out;
    char* ws = (char*)d_ws;
    if (ws_size < (size_t)WS_NEED) return;

    ushort* kt = (ushort*)(ws + OFF_KT);
    ushort* v4 = (ushort*)(ws + OFF_V4);

    prep<<<2176, 256, 0, stream>>>(k, v, kt, v4);
    attn<<<1152, 64, 0, stream>>>(q, kt, v4, out);
}